// Round 1
// baseline (843.648 us; speedup 1.0000x reference)
//
#include <hip/hip_runtime.h>
#include <math.h>

#define B_      128
#define NNODES  2047   // 2*1024-1
#define NL_     64
#define DIN     512

typedef __attribute__((ext_vector_type(8))) short short8;   // 8 bf16 (4 VGPRs)
typedef __attribute__((ext_vector_type(4))) float v4f;      // MFMA accumulator

// fp32 -> bf16 round-to-nearest-even
static __device__ inline unsigned short f2bf(float x) {
    unsigned u = __float_as_uint(x);
    u = (u + 0x7FFFu + ((u >> 16) & 1u)) >> 16;
    return (unsigned short)u;
}

// ---------------------------------------------------------------------------
// Kernel 1 (merged prep): E = exp(trans) (4096 elems) and
// Wt[n][k] = bf16(W[k][n]) (32768 elems). Grid 128x256 covers both.
// ---------------------------------------------------------------------------
__global__ __launch_bounds__(256) void kprep(const float* __restrict__ W,
                                             const float* __restrict__ trans,
                                             unsigned short* __restrict__ Wt,
                                             float* __restrict__ E) {
    int i = blockIdx.x * 256 + threadIdx.x;   // 0..32767
    if (i < NL_ * NL_) E[i] = __expf(trans[i]);
    int k = i >> 6, n = i & 63;
    Wt[n * DIN + k] = f2bf(W[i]);
}

// ---------------------------------------------------------------------------
// Kernel 2: emis = hidden @ W + b via bf16 MFMA (M=262016, K=512, N=64).
// Barrier-free register-streaming version:
//   - no LDS at all. A fragments: global fp32 -> VGPR -> f2bf, per-lane
//     addresses already in MFMA A-frag layout (m=lane&15, k=quad*8+j).
//   - B fragments read directly from global Wt (64 KB, L1/L2-resident),
//     layout n=lane&15, k=quad*8+j — same elements the old LDS path fed.
//   - wave owns 32 rows x 64 cols (2 m-tiles x 4 n-tiles, acc = 32 VGPR);
//     block = 4 waves = 128 rows; grid = 262016/128 = 2047 exactly.
//   - ping-pong prefetch: chunk kc+32 (and kc+64) in flight while MFMA
//     consumes chunk kc. Zero __syncthreads in the whole kernel.
// D mapping: col=lane&15, row=quad*4+reg (m89/m91-verified, unchanged).
// ---------------------------------------------------------------------------
struct Abuf { float4 x0, x1, y0, y1; };          // 2 m-tiles x 8 floats
struct Bbuf { uint4 b0, b1, b2, b3; };           // 4 n-tiles x 8 bf16

static __device__ inline void loadA(const float* __restrict__ a0,
                                    const float* __restrict__ a1,
                                    int off, Abuf& A) {
    A.x0 = *(const float4*)(a0 + off);
    A.x1 = *(const float4*)(a0 + off + 4);
    A.y0 = *(const float4*)(a1 + off);
    A.y1 = *(const float4*)(a1 + off + 4);
}

static __device__ inline void loadB(const unsigned short* __restrict__ bp,
                                    int off, Bbuf& Bb) {
    Bb.b0 = *(const uint4*)(bp + off);
    Bb.b1 = *(const uint4*)(bp + off + 16 * DIN);
    Bb.b2 = *(const uint4*)(bp + off + 32 * DIN);
    Bb.b3 = *(const uint4*)(bp + off + 48 * DIN);
}

static __device__ inline short8 cvt8(float4 u, float4 v) {
    short8 r;
    unsigned short* p = (unsigned short*)&r;
    p[0] = f2bf(u.x); p[1] = f2bf(u.y); p[2] = f2bf(u.z); p[3] = f2bf(u.w);
    p[4] = f2bf(v.x); p[5] = f2bf(v.y); p[6] = f2bf(v.z); p[7] = f2bf(v.w);
    return r;
}

static __device__ inline void mac(const Abuf& A, const Bbuf& Bb, v4f acc[2][4]) {
    short8 af0 = cvt8(A.x0, A.x1);
    short8 af1 = cvt8(A.y0, A.y1);
    short8 bf;
    bf = *(const short8*)&Bb.b0;
    acc[0][0] = __builtin_amdgcn_mfma_f32_16x16x32_bf16(af0, bf, acc[0][0], 0, 0, 0);
    acc[1][0] = __builtin_amdgcn_mfma_f32_16x16x32_bf16(af1, bf, acc[1][0], 0, 0, 0);
    bf = *(const short8*)&Bb.b1;
    acc[0][1] = __builtin_amdgcn_mfma_f32_16x16x32_bf16(af0, bf, acc[0][1], 0, 0, 0);
    acc[1][1] = __builtin_amdgcn_mfma_f32_16x16x32_bf16(af1, bf, acc[1][1], 0, 0, 0);
    bf = *(const short8*)&Bb.b2;
    acc[0][2] = __builtin_amdgcn_mfma_f32_16x16x32_bf16(af0, bf, acc[0][2], 0, 0, 0);
    acc[1][2] = __builtin_amdgcn_mfma_f32_16x16x32_bf16(af1, bf, acc[1][2], 0, 0, 0);
    bf = *(const short8*)&Bb.b3;
    acc[0][3] = __builtin_amdgcn_mfma_f32_16x16x32_bf16(af0, bf, acc[0][3], 0, 0, 0);
    acc[1][3] = __builtin_amdgcn_mfma_f32_16x16x32_bf16(af1, bf, acc[1][3], 0, 0, 0);
}

__global__ __launch_bounds__(256) void kgemm(const float* __restrict__ H,
                                             const unsigned short* __restrict__ Wt,
                                             const float* __restrict__ bias,
                                             float* __restrict__ emis) {
    int t    = threadIdx.x;
    int lane = t & 63;
    int w    = t >> 6;
    int ln   = lane & 15;
    int quad = lane >> 4;
    long rowBase = (long)blockIdx.x * 128 + w * 32;   // wave's first row

    const float* a0 = H + (rowBase + ln) * DIN + quad * 8;       // m-tile 0
    const float* a1 = a0 + 16 * DIN;                             // m-tile 1
    const unsigned short* bp = Wt + ln * DIN + quad * 8;

    v4f acc[2][4];
    #pragma unroll
    for (int mt = 0; mt < 2; ++mt)
        #pragma unroll
        for (int nt = 0; nt < 4; ++nt)
            acc[mt][nt] = (v4f){0.f, 0.f, 0.f, 0.f};

    Abuf A0, A1; Bbuf Bb0, Bb1;
    loadA(a0, a1, 0, A0);
    loadB(bp, 0, Bb0);

    #pragma unroll
    for (int kc = 0; kc < DIN; kc += 64) {
        loadA(a0, a1, kc + 32, A1);
        loadB(bp, kc + 32, Bb1);
        mac(A0, Bb0, acc);                    // chunk kc
        if (kc + 64 < DIN) {
            loadA(a0, a1, kc + 64, A0);
            loadB(bp, kc + 64, Bb0);
        }
        mac(A1, Bb1, acc);                    // chunk kc+32
    }

    // epilogue: + bias, store fp32 (row=quad*4+rg, col=lane&15)
    #pragma unroll
    for (int nt = 0; nt < 4; ++nt) {
        float bv = bias[nt * 16 + ln];
        #pragma unroll
        for (int mt = 0; mt < 2; ++mt) {
            #pragma unroll
            for (int rg = 0; rg < 4; ++rg) {
                long row = rowBase + mt * 16 + quad * 4 + rg;
                emis[row * NL_ + nt * 16 + ln] = acc[mt][nt][rg] + bv;
            }
        }
    }
}

// ---------------------------------------------------------------------------
// Kernel 3: one tree level, lane-per-task, 2048 waves (2/SIMD).
// J = 2048/groups splits the j-loop across waves; parent-row RMW is float4.
// ---------------------------------------------------------------------------
__global__ __launch_bounds__(64, 2) void klevel(float* __restrict__ inside,
                                                const float* __restrict__ E,
                                                int d) {
    int lane   = threadIdx.x;
    int n      = 1 << d;
    int groups = (B_ << d) >> 6;      // tasks / 64
    int J      = 2048 / groups;       // j-split factor (d9:2 .. d6:16)
    int jw     = 64 / J;              // j's per wave (>=4)
    int tg     = blockIdx.x / J;
    int j0     = (blockIdx.x % J) * jw;

    int task = tg * 64 + lane;
    int b    = task >> d;
    int i    = task & (n - 1);
    int g    = n - 1 + i;
    int rowL = (b * NNODES + 2 * g + 1) << 6;  // left child row; right = +64
    int rowG = (b * NNODES + g) << 6;

    float el[64], er[64];
    const float4* pC = (const float4*)(inside + rowL);
    #pragma unroll
    for (int q = 0; q < 16; ++q) {
        float4 v = pC[q];
        el[4*q] = v.x; el[4*q+1] = v.y; el[4*q+2] = v.z; el[4*q+3] = v.w;
    }
    #pragma unroll
    for (int q = 0; q < 16; ++q) {
        float4 v = pC[16 + q];
        er[4*q] = v.x; er[4*q+1] = v.y; er[4*q+2] = v.z; er[4*q+3] = v.w;
    }
    float ml = el[0], mr = er[0];
    #pragma unroll
    for (int k = 1; k < 64; ++k) { ml = fmaxf(ml, el[k]); mr = fmaxf(mr, er[k]); }
    #pragma unroll
    for (int k = 0; k < 64; ++k) {
        el[k] = __expf(el[k] - ml);
        er[k] = __expf(er[k] - mr);
    }
    float mbase = ml + mr;

    for (int j4 = 0; j4 < jw; j4 += 4) {
        float res[4];
        #pragma unroll
        for (int jj = 0; jj < 4; ++jj) {
            const float4* Er = (const float4*)(E + ((j0 + j4 + jj) << 6)); // uniform
            float accl = 0.f, accr = 0.f;
            #pragma unroll
            for (int q = 0; q < 16; ++q) {
                float4 e = Er[q];
                accl = fmaf(el[4*q+0], e.x, accl); accl = fmaf(el[4*q+1], e.y, accl);
                accl = fmaf(el[4*q+2], e.z, accl); accl = fmaf(el[4*q+3], e.w, accl);
                accr = fmaf(er[4*q+0], e.x, accr); accr = fmaf(er[4*q+1], e.y, accr);
                accr = fmaf(er[4*q+2], e.z, accr); accr = fmaf(er[4*q+3], e.w, accr);
            }
            res[jj] = mbase + __logf(accl) + __logf(accr);
        }
        float4* pg = (float4*)(inside + rowG + j0 + j4);
        float4 ev = *pg;
        ev.x += res[0]; ev.y += res[1]; ev.z += res[2]; ev.w += res[3];
        *pg = ev;
    }
}

// ---------------------------------------------------------------------------
// Kernel 4: fused tail, levels d=5..0. One block per batch, wave-per-task,
// E row j in lane j's registers, readlane broadcast. Level 0 -> d_out.
// ---------------------------------------------------------------------------
__global__ __launch_bounds__(256) void ktail(float* __restrict__ inside,
                                             const float* __restrict__ E,
                                             float* __restrict__ out) {
    int b    = blockIdx.x;
    int lane = threadIdx.x & 63;
    int wid  = threadIdx.x >> 6;

    float Ereg[64];
    const float4* E4 = (const float4*)(E + lane * NL_);
    #pragma unroll
    for (int q = 0; q < 16; ++q) {
        float4 v = E4[q];
        Ereg[4*q] = v.x; Ereg[4*q+1] = v.y; Ereg[4*q+2] = v.z; Ereg[4*q+3] = v.w;
    }
    int base = b * NNODES;

    for (int d = 5; d >= 0; --d) {
        int n = 1 << d;
        for (int i = wid; i < n; i += 4) {
            int g    = n - 1 + i;
            int rowC = (base + 2 * g + 1) << 6;
            float lf = inside[rowC + lane];
            float rf = inside[rowC + 64 + lane];
            float ml = lf, mr = rf;
            #pragma unroll
            for (int s = 32; s >= 1; s >>= 1) {
                ml = fmaxf(ml, __shfl_xor(ml, s));
                mr = fmaxf(mr, __shfl_xor(mr, s));
            }
            float el = __expf(lf - ml);
            float er = __expf(rf - mr);
            float accl = 0.f, accr = 0.f;
            #pragma unroll
            for (int k = 0; k < 64; ++k) {
                float ek = __int_as_float(__builtin_amdgcn_readlane(__float_as_int(el), k));
                float rk = __int_as_float(__builtin_amdgcn_readlane(__float_as_int(er), k));
                accl = fmaf(ek, Ereg[k], accl);
                accr = fmaf(rk, Ereg[k], accr);
            }
            int rowG  = (base + g) << 6;
            float res = inside[rowG + lane] + ml + mr + __logf(accl) + __logf(accr);
            if (d == 0) out[b * NL_ + lane] = res;
            else        inside[rowG + lane] = res;
        }
        __syncthreads();
    }
}

// ---------------------------------------------------------------------------
// Launch. ws layout: [E: 4096 f][Wt bf16: 32768 us = 16384 f][inside: 16.7M f]
// ---------------------------------------------------------------------------
extern "C" void kernel_launch(void* const* d_in, const int* in_sizes, int n_in,
                              void* d_out, int out_size, void* d_ws, size_t ws_size,
                              hipStream_t stream) {
    const float* hidden = (const float*)d_in[0];
    const float* W      = (const float*)d_in[1];
    const float* bias   = (const float*)d_in[2];
    const float* trans  = (const float*)d_in[3];
    float* out = (float*)d_out;
    float* E   = (float*)d_ws;
    unsigned short* Wt = (unsigned short*)(E + NL_ * NL_);
    float* inside = E + NL_ * NL_ + (DIN * NL_ / 2);

    kprep<<<(DIN * NL_) / 256, 256, 0, stream>>>(W, trans, Wt, E);
    kgemm<<<(B_ * NNODES) / 128, 256, 0, stream>>>(hidden, Wt, bias, inside);
    for (int d = 9; d >= 6; --d)
        klevel<<<2048, 64, 0, stream>>>(inside, E, d);
    ktail<<<B_, 256, 0, stream>>>(inside, E, out);
}

// Round 2
// 812.206 us; speedup vs baseline: 1.0387x; 1.0387x over previous
//
#include <hip/hip_runtime.h>
#include <math.h>

#define B_      128
#define NNODES  2047   // 2*1024-1
#define NL_     64
#define DIN     512

typedef __attribute__((ext_vector_type(8))) short short8;   // 8 bf16 (4 VGPRs)
typedef __attribute__((ext_vector_type(4))) float v4f;      // MFMA accumulator

// fp32 -> bf16 round-to-nearest-even
static __device__ inline unsigned short f2bf(float x) {
    unsigned u = __float_as_uint(x);
    u = (u + 0x7FFFu + ((u >> 16) & 1u)) >> 16;
    return (unsigned short)u;
}

// ---------------------------------------------------------------------------
// Kernel 1 (merged prep): E = exp(trans) (4096 elems) and
// Wt[n][k] = bf16(W[k][n]) (32768 elems).
// ---------------------------------------------------------------------------
__global__ __launch_bounds__(256) void kprep(const float* __restrict__ W,
                                             const float* __restrict__ trans,
                                             unsigned short* __restrict__ Wt,
                                             float* __restrict__ E) {
    int i = blockIdx.x * 256 + threadIdx.x;   // 0..32767
    if (i < NL_ * NL_) E[i] = __expf(trans[i]);
    int k = i >> 6, n = i & 63;
    Wt[n * DIN + k] = f2bf(W[i]);
}

// ---------------------------------------------------------------------------
// Kernel 2: emis = hidden @ W + b via bf16 MFMA (M=262016, K=512, N=64).
// (Reverted to the proven LDS-staged version from the 824.8 us config —
//  the round-1 register-streaming variant was ~18 us slower.)
// Block 256 thr = 4 waves; 64-row x 64-col tile; K chunks of 64.
// LDS rows padded to 72 bf16 (144 B): frag b128 reads land 2-way/bank = free.
// D: col=lane&15, row=quad*4+reg (m89/m91-verified mapping).
// ---------------------------------------------------------------------------
__global__ __launch_bounds__(256) void kgemm(const float* __restrict__ H,
                                             const unsigned short* __restrict__ Wt,
                                             const float* __restrict__ bias,
                                             float* __restrict__ emis) {
    __shared__ unsigned short Al[64 * 72];
    __shared__ unsigned short Wl[64 * 72];
    int t = threadIdx.x;
    int rowBase = blockIdx.x * 64;
    int lane = t & 63;
    int w    = t >> 6;        // wave id -> row group
    int ln   = lane & 15;
    int quad = lane >> 4;

    v4f acc[4];
    #pragma unroll
    for (int i = 0; i < 4; ++i) acc[i] = (v4f){0.f, 0.f, 0.f, 0.f};

    int r   = t >> 2;         // staging row (A) / n (W)
    int sub = t & 3;
    const float* hrow = H + (long)(rowBase + r) * DIN + sub * 16;
    const unsigned short* wrow = Wt + r * DIN + sub * 8;

    for (int kc = 0; kc < DIN; kc += 64) {
        __syncthreads();
        // --- stage A: 64 rows x 64 k, fp32 -> bf16 ---
        #pragma unroll
        for (int i = 0; i < 4; ++i) {
            float4 v = *(const float4*)(hrow + kc + i * 4);
            unsigned long long pk =
                (unsigned long long)f2bf(v.x)
              | ((unsigned long long)f2bf(v.y) << 16)
              | ((unsigned long long)f2bf(v.z) << 32)
              | ((unsigned long long)f2bf(v.w) << 48);
            *(unsigned long long*)&Al[r * 72 + sub * 16 + i * 4] = pk;
        }
        // --- stage W: 64 n x 64 k bf16 copy ---
        #pragma unroll
        for (int i = 0; i < 2; ++i) {
            uint4 wv = *(const uint4*)(wrow + kc + i * 32);
            *(uint4*)&Wl[r * 72 + sub * 8 + i * 32] = wv;
        }
        __syncthreads();
        // --- MFMA: 2 k-sub of 32, 4 n-tiles ---
        const unsigned short* Ab = &Al[(w * 16 + ln) * 72];
        const unsigned short* Wb = &Wl[ln * 72];
        #pragma unroll
        for (int ks = 0; ks < 2; ++ks) {
            short8 af = *(const short8*)(Ab + ks * 32 + quad * 8);
            #pragma unroll
            for (int nt = 0; nt < 4; ++nt) {
                short8 bf = *(const short8*)(Wb + nt * 16 * 72 + ks * 32 + quad * 8);
                acc[nt] = __builtin_amdgcn_mfma_f32_16x16x32_bf16(af, bf, acc[nt], 0, 0, 0);
            }
        }
    }
    // --- epilogue: + bias, store fp32 ---
    #pragma unroll
    for (int nt = 0; nt < 4; ++nt) {
        float bv = bias[nt * 16 + ln];
        #pragma unroll
        for (int rg = 0; rg < 4; ++rg) {
            int row = rowBase + w * 16 + quad * 4 + rg;
            emis[(long)row * NL_ + nt * 16 + ln] = acc[nt][rg] + bv;
        }
    }
}

// ---------------------------------------------------------------------------
// Kernel 3 v2: one tree level, block-tiled.
// Block = 256 thr handles 64 parents of one batch; their 128 children rows
// are CONTIGUOUS in memory -> coalesced 32 KB LDS stage. XOR-swizzle on
// parent index p=row>>1 makes phase-B row-per-lane ds_read_b128 conflict-free
// (slot' = slot ^ (p&15): 8 bank-groups x 8 lanes = uniform 8/bank).
// Phase A: exp computed ONCE per child row (2 thr/row, shfl-combined max).
// Phase B: lane = parent, wave+js = j-slice of JW j's (compile-time -> regs).
// FMA k-order ascending == old kernel -> bitwise-identical results.
// Grid = groups * JS where JS = 16/JW; always 1024 blocks (16 waves/CU).
// ---------------------------------------------------------------------------
template<int JW>
__global__ __launch_bounds__(256, 4) void klevel2(float* __restrict__ inside,
                                                  const float* __restrict__ E,
                                                  int d) {
    constexpr int JS = 16 / JW;
    __shared__ float Ls[128 * 64];
    __shared__ float ms[128];
    int t = threadIdx.x;
    int n = 1 << d;
    int gpb = n >> 6;                   // 64-parent groups per batch (>=1 for d>=6)
    int group = blockIdx.x / JS;
    int js    = blockIdx.x - group * JS;
    int b  = group / gpb;
    int i0 = (group - b * gpb) << 6;
    int g0 = n - 1 + i0;                // first parent node of this group
    long cbase = ((long)(b * NNODES + 2 * g0 + 1)) << 6;  // first child row, float idx

    // --- stage: 128 contiguous child rows (32 KB), swizzled into LDS ---
    const float4* src = (const float4*)(inside + cbase);
    #pragma unroll
    for (int it = 0; it < 8; ++it) {
        int q   = t + it * 256;         // float4 index 0..2047
        int row = q >> 4, slot = q & 15;
        float4 v = src[q];
        *(float4*)&Ls[row * 64 + ((slot ^ ((row >> 1) & 15)) << 2)] = v;
    }
    __syncthreads();

    // --- phase A: per-row max + exp in place (2 threads per row) ---
    {
        int row  = t >> 1, half = t & 1;
        int pk   = (row >> 1) & 15;
        float vals[32];
        #pragma unroll
        for (int q = 0; q < 8; ++q) {
            int slot = half * 8 + q;
            float4 v = *(const float4*)&Ls[row * 64 + ((slot ^ pk) << 2)];
            vals[4*q] = v.x; vals[4*q+1] = v.y; vals[4*q+2] = v.z; vals[4*q+3] = v.w;
        }
        float m = vals[0];
        #pragma unroll
        for (int k = 1; k < 32; ++k) m = fmaxf(m, vals[k]);
        m = fmaxf(m, __shfl_xor(m, 1));
        #pragma unroll
        for (int k = 0; k < 32; ++k) vals[k] = __expf(vals[k] - m);
        #pragma unroll
        for (int q = 0; q < 8; ++q) {
            int slot = half * 8 + q;
            *(float4*)&Ls[row * 64 + ((slot ^ pk) << 2)] =
                (float4){vals[4*q], vals[4*q+1], vals[4*q+2], vals[4*q+3]};
        }
        if (half == 0) ms[row] = m;
    }
    __syncthreads();

    // --- phase B: lane = parent p, (js,wave) = slice of JW j's ---
    int p  = t & 63;
    int w  = t >> 6;
    int j0 = (js * 4 + w) * JW;
    float accl[JW], accr[JW];
    #pragma unroll
    for (int j = 0; j < JW; ++j) { accl[j] = 0.f; accr[j] = 0.f; }

    #pragma unroll
    for (int c = 0; c < 4; ++c) {       // k-chunks of 16
        float el[16], er[16];
        #pragma unroll
        for (int q = 0; q < 4; ++q) {
            int sl = ((c * 4 + q) ^ (p & 15)) << 2;
            float4 v = *(const float4*)&Ls[(2 * p)     * 64 + sl];
            float4 u = *(const float4*)&Ls[(2 * p + 1) * 64 + sl];
            el[4*q]=v.x; el[4*q+1]=v.y; el[4*q+2]=v.z; el[4*q+3]=v.w;
            er[4*q]=u.x; er[4*q+1]=u.y; er[4*q+2]=u.z; er[4*q+3]=u.w;
        }
        #pragma unroll
        for (int j = 0; j < JW; ++j) {
            const float4* Er = (const float4*)(E + ((j0 + j) << 6) + c * 16);
            #pragma unroll
            for (int q = 0; q < 4; ++q) {
                float4 e = Er[q];
                accl[j] = fmaf(el[4*q+0], e.x, accl[j]);
                accl[j] = fmaf(el[4*q+1], e.y, accl[j]);
                accl[j] = fmaf(el[4*q+2], e.z, accl[j]);
                accl[j] = fmaf(el[4*q+3], e.w, accl[j]);
                accr[j] = fmaf(er[4*q+0], e.x, accr[j]);
                accr[j] = fmaf(er[4*q+1], e.y, accr[j]);
                accr[j] = fmaf(er[4*q+2], e.z, accr[j]);
                accr[j] = fmaf(er[4*q+3], e.w, accr[j]);
            }
        }
    }

    float mbase = ms[2 * p] + ms[2 * p + 1];
    #pragma unroll
    for (int j = 0; j < JW; ++j)
        accl[j] = mbase + __logf(accl[j]) + __logf(accr[j]);

    long prow = ((long)(b * NNODES + g0 + p)) << 6;
    if constexpr (JW >= 4) {
        #pragma unroll
        for (int j4 = 0; j4 < JW; j4 += 4) {
            float4* pg = (float4*)(inside + prow + j0 + j4);
            float4 ev = *pg;
            ev.x += accl[j4]; ev.y += accl[j4+1];
            ev.z += accl[j4+2]; ev.w += accl[j4+3];
            *pg = ev;
        }
    } else {
        float2* pg = (float2*)(inside + prow + j0);
        float2 ev = *pg;
        ev.x += accl[0]; ev.y += accl[1];
        *pg = ev;
    }
}

// ---------------------------------------------------------------------------
// Kernel 4: fused tail, levels d=5..0. One block per batch, wave-per-task,
// E row j in lane j's registers, readlane broadcast. Level 0 -> d_out.
// ---------------------------------------------------------------------------
__global__ __launch_bounds__(256) void ktail(float* __restrict__ inside,
                                             const float* __restrict__ E,
                                             float* __restrict__ out) {
    int b    = blockIdx.x;
    int lane = threadIdx.x & 63;
    int wid  = threadIdx.x >> 6;

    float Ereg[64];
    const float4* E4 = (const float4*)(E + lane * NL_);
    #pragma unroll
    for (int q = 0; q < 16; ++q) {
        float4 v = E4[q];
        Ereg[4*q] = v.x; Ereg[4*q+1] = v.y; Ereg[4*q+2] = v.z; Ereg[4*q+3] = v.w;
    }
    int base = b * NNODES;

    for (int d = 5; d >= 0; --d) {
        int n = 1 << d;
        for (int i = wid; i < n; i += 4) {
            int g    = n - 1 + i;
            int rowC = (base + 2 * g + 1) << 6;
            float lf = inside[rowC + lane];
            float rf = inside[rowC + 64 + lane];
            float ml = lf, mr = rf;
            #pragma unroll
            for (int s = 32; s >= 1; s >>= 1) {
                ml = fmaxf(ml, __shfl_xor(ml, s));
                mr = fmaxf(mr, __shfl_xor(mr, s));
            }
            float el = __expf(lf - ml);
            float er = __expf(rf - mr);
            float accl = 0.f, accr = 0.f;
            #pragma unroll
            for (int k = 0; k < 64; ++k) {
                float ek = __int_as_float(__builtin_amdgcn_readlane(__float_as_int(el), k));
                float rk = __int_as_float(__builtin_amdgcn_readlane(__float_as_int(er), k));
                accl = fmaf(ek, Ereg[k], accl);
                accr = fmaf(rk, Ereg[k], accr);
            }
            int rowG  = (base + g) << 6;
            float res = inside[rowG + lane] + ml + mr + __logf(accl) + __logf(accr);
            if (d == 0) out[b * NL_ + lane] = res;
            else        inside[rowG + lane] = res;
        }
        __syncthreads();
    }
}

// ---------------------------------------------------------------------------
// Launch. ws layout: [E: 4096 f][Wt bf16: 32768 us = 16384 f][inside: 16.7M f]
// ---------------------------------------------------------------------------
extern "C" void kernel_launch(void* const* d_in, const int* in_sizes, int n_in,
                              void* d_out, int out_size, void* d_ws, size_t ws_size,
                              hipStream_t stream) {
    const float* hidden = (const float*)d_in[0];
    const float* W      = (const float*)d_in[1];
    const float* bias   = (const float*)d_in[2];
    const float* trans  = (const float*)d_in[3];
    float* out = (float*)d_out;
    float* E   = (float*)d_ws;
    unsigned short* Wt = (unsigned short*)(E + NL_ * NL_);
    float* inside = E + NL_ * NL_ + (DIN * NL_ / 2);

    kprep<<<(DIN * NL_) / 256, 256, 0, stream>>>(W, trans, Wt, E);
    kgemm<<<(B_ * NNODES) / 64, 256, 0, stream>>>(hidden, Wt, bias, inside);
    // tree levels d=9..6: groups = B*n/64, JS = 16/JW, grid always 1024
    klevel2<16><<<((B_ << 9) >> 6) * 1, 256, 0, stream>>>(inside, E, 9);
    klevel2< 8><<<((B_ << 8) >> 6) * 2, 256, 0, stream>>>(inside, E, 8);
    klevel2< 4><<<((B_ << 7) >> 6) * 4, 256, 0, stream>>>(inside, E, 7);
    klevel2< 2><<<((B_ << 6) >> 6) * 8, 256, 0, stream>>>(inside, E, 6);
    ktail<<<B_, 256, 0, stream>>>(inside, E, out);
}

// Round 3
// 810.986 us; speedup vs baseline: 1.0403x; 1.0015x over previous
//
#include <hip/hip_runtime.h>
#include <math.h>

#define B_      128
#define NNODES  2047   // 2*1024-1
#define NL_     64
#define DIN     512

typedef __attribute__((ext_vector_type(8))) short short8;   // 8 bf16 (4 VGPRs)
typedef __attribute__((ext_vector_type(4))) float v4f;      // MFMA accumulator

// async global->LDS DMA, 16B per lane; LDS dest = wave-uniform base + lane*16
#define GLL(g, l) __builtin_amdgcn_global_load_lds(                      \
    (const __attribute__((address_space(1))) void*)(g),                  \
    (__attribute__((address_space(3))) void*)(l), 16, 0, 0)

// fp32 -> bf16 round-to-nearest-even
static __device__ inline unsigned short f2bf(float x) {
    unsigned u = __float_as_uint(x);
    u = (u + 0x7FFFu + ((u >> 16) & 1u)) >> 16;
    return (unsigned short)u;
}

static __device__ inline short8 cvt8(float4 u, float4 v) {
    short8 r;
    unsigned short* p = (unsigned short*)&r;
    p[0] = f2bf(u.x); p[1] = f2bf(u.y); p[2] = f2bf(u.z); p[3] = f2bf(u.w);
    p[4] = f2bf(v.x); p[5] = f2bf(v.y); p[6] = f2bf(v.z); p[7] = f2bf(v.w);
    return r;
}

// ---------------------------------------------------------------------------
// Kernel 1 (merged prep): E = exp(trans) (4096 elems) and
// Wt[n][k] = bf16(W[k][n]) (32768 elems).
// ---------------------------------------------------------------------------
__global__ __launch_bounds__(256) void kprep(const float* __restrict__ W,
                                             const float* __restrict__ trans,
                                             unsigned short* __restrict__ Wt,
                                             float* __restrict__ E) {
    int i = blockIdx.x * 256 + threadIdx.x;   // 0..32767
    if (i < NL_ * NL_) E[i] = __expf(trans[i]);
    int k = i >> 6, n = i & 63;
    Wt[n * DIN + k] = f2bf(W[i]);
}

// ---------------------------------------------------------------------------
// Kernel 2 v3: emis = hidden @ W + b via bf16 MFMA (M=262016, K=512, N=64).
// global_load_lds DMA staging (no VGPR round-trip, no VALU in stage path),
// double-buffered, ONE barrier per K-chunk (T3 minimum-2-phase):
//   prologue: STAGE(buf0,chunk0); sync;
//   loop:     STAGE(buf^1,next); COMPUTE(buf); sync; swap;
// A staged as fp32 [64 rows][16 slots of 16B], source-XOR-swizzled
// (slot' = slot ^ (row&15)) -> frag ds_reads land 2 lanes/bank = free.
// W staged bf16 [64 n][8 slots], slot' = slot ^ (row&7) -> 2-way = free.
// f2bf conversion moved to fragment-read (same element count as before,
// same RNE, same MFMA order -> bitwise-identical to previous kernel).
// LDS 48 KB -> 3 blocks/CU. D: col=lane&15, row=quad*4+reg.
// ---------------------------------------------------------------------------
__global__ __launch_bounds__(256) void kgemm(const float* __restrict__ H,
                                             const unsigned short* __restrict__ Wt,
                                             const float* __restrict__ bias,
                                             float* __restrict__ emis) {
    __shared__ float Af[2][64 * 64];           // 2 x 16 KB, fp32 A chunk
    __shared__ unsigned short Wl[2][64 * 64];  // 2 x 8 KB, bf16 W chunk
    int t    = threadIdx.x;
    int lane = t & 63;
    int w    = t >> 6;
    int ln   = lane & 15;
    int quad = lane >> 4;
    long rowBase = (long)blockIdx.x * 64;

    // per-thread swizzled global source addresses (fixed across chunks)
    const float* asrc[4];
    #pragma unroll
    for (int i = 0; i < 4; ++i) {
        int q = i * 256 + t, row = q >> 4, s = q & 15;
        asrc[i] = H + (rowBase + row) * DIN + ((s ^ (row & 15)) << 2);
    }
    const unsigned short* wsrc[2];
    #pragma unroll
    for (int i = 0; i < 2; ++i) {
        int q = i * 256 + t, row = q >> 3, s = q & 7;
        wsrc[i] = Wt + row * DIN + ((s ^ (row & 7)) << 3);
    }
    int woff = w * 1024;   // wave-uniform LDS byte offset within a 4KB issue

    v4f acc[4];
    #pragma unroll
    for (int i = 0; i < 4; ++i) acc[i] = (v4f){0.f, 0.f, 0.f, 0.f};

    // prologue: stage chunk 0 into buf 0
    #pragma unroll
    for (int i = 0; i < 4; ++i) GLL(asrc[i], (char*)&Af[0][0] + i * 4096 + woff);
    #pragma unroll
    for (int i = 0; i < 2; ++i) GLL(wsrc[i], (char*)&Wl[0][0] + i * 4096 + woff);
    __syncthreads();

    int cur = 0;
    #pragma unroll
    for (int kc = 0; kc < DIN; kc += 64) {
        if (kc + 64 < DIN) {   // stage next chunk into the other buffer
            #pragma unroll
            for (int i = 0; i < 4; ++i)
                GLL(asrc[i] + kc + 64, (char*)&Af[cur ^ 1][0] + i * 4096 + woff);
            #pragma unroll
            for (int i = 0; i < 2; ++i)
                GLL(wsrc[i] + kc + 64, (char*)&Wl[cur ^ 1][0] + i * 4096 + woff);
        }
        // compute on current buffer
        const char* Ab = (const char*)&Af[cur][0] + (w * 16 + ln) * 256;
        const char* Wb = (const char*)&Wl[cur][0];
        #pragma unroll
        for (int ks = 0; ks < 2; ++ks) {
            int s0 = ks * 8 + quad * 2;
            float4 alo = *(const float4*)(Ab + ((s0 ^ ln) << 4));
            float4 ahi = *(const float4*)(Ab + (((s0 + 1) ^ ln) << 4));
            short8 af = cvt8(alo, ahi);
            #pragma unroll
            for (int nt = 0; nt < 4; ++nt) {
                const char* Wr = Wb + (nt * 16 + ln) * 128;
                short8 bf = *(const short8*)(Wr + (((ks * 4 + quad) ^ (ln & 7)) << 4));
                acc[nt] = __builtin_amdgcn_mfma_f32_16x16x32_bf16(af, bf, acc[nt], 0, 0, 0);
            }
        }
        __syncthreads();   // drains stage DMA (next buf ready) + protects reuse
        cur ^= 1;
    }

    // epilogue: + bias, store fp32 (row=quad*4+rg, col=lane&15)
    #pragma unroll
    for (int nt = 0; nt < 4; ++nt) {
        float bv = bias[nt * 16 + ln];
        #pragma unroll
        for (int rg = 0; rg < 4; ++rg) {
            long row = rowBase + w * 16 + quad * 4 + rg;
            emis[row * NL_ + nt * 16 + ln] = acc[nt][rg] + bv;
        }
    }
}

// ---------------------------------------------------------------------------
// Kernel 3 v2b: one tree level, block-tiled; stage now via global_load_lds
// with source-XOR-swizzle (linear LDS dest; same involution as the read side,
// so the staged layout is bit-identical to v2's write-side swizzle).
// Block = 256 thr handles 64 parents; 128 contiguous child rows -> 32 KB LDS.
// Phase A: exp ONCE per child row (2 thr/row). Phase B: lane=parent,
// (js,wave)=JW-j slice, compile-time JW. FMA k-order unchanged.
// ---------------------------------------------------------------------------
template<int JW>
__global__ __launch_bounds__(256, 4) void klevel2(float* __restrict__ inside,
                                                  const float* __restrict__ E,
                                                  int d) {
    constexpr int JS = 16 / JW;
    __shared__ float Ls[128 * 64];
    __shared__ float ms[128];
    int t = threadIdx.x;
    int n = 1 << d;
    int gpb = n >> 6;                   // 64-parent groups per batch (>=1 for d>=6)
    int group = blockIdx.x / JS;
    int js    = blockIdx.x - group * JS;
    int b  = group / gpb;
    int i0 = (group - b * gpb) << 6;
    int g0 = n - 1 + i0;                // first parent node of this group
    long cbase = ((long)(b * NNODES + 2 * g0 + 1)) << 6;  // first child row, float idx

    // --- stage: 128 contiguous child rows (32 KB) via DMA, source-swizzled ---
    const float* srcf = inside + cbase;
    int wv = t >> 6;
    #pragma unroll
    for (int it = 0; it < 8; ++it) {
        int q = it * 256 + t;           // 16B-slot index 0..2047
        int row = q >> 4, s = q & 15;
        GLL(srcf + row * 64 + ((s ^ ((row >> 1) & 15)) << 2),
            (char*)Ls + it * 4096 + wv * 1024);
    }
    __syncthreads();

    // --- phase A: per-row max + exp in place (2 threads per row) ---
    {
        int row  = t >> 1, half = t & 1;
        int pk   = (row >> 1) & 15;
        float vals[32];
        #pragma unroll
        for (int q = 0; q < 8; ++q) {
            int slot = half * 8 + q;
            float4 v = *(const float4*)&Ls[row * 64 + ((slot ^ pk) << 2)];
            vals[4*q] = v.x; vals[4*q+1] = v.y; vals[4*q+2] = v.z; vals[4*q+3] = v.w;
        }
        float m = vals[0];
        #pragma unroll
        for (int k = 1; k < 32; ++k) m = fmaxf(m, vals[k]);
        m = fmaxf(m, __shfl_xor(m, 1));
        #pragma unroll
        for (int k = 0; k < 32; ++k) vals[k] = __expf(vals[k] - m);
        #pragma unroll
        for (int q = 0; q < 8; ++q) {
            int slot = half * 8 + q;
            *(float4*)&Ls[row * 64 + ((slot ^ pk) << 2)] =
                (float4){vals[4*q], vals[4*q+1], vals[4*q+2], vals[4*q+3]};
        }
        if (half == 0) ms[row] = m;
    }
    __syncthreads();

    // --- phase B: lane = parent p, (js,wave) = slice of JW j's ---
    int p  = t & 63;
    int w  = t >> 6;
    int j0 = (js * 4 + w) * JW;
    float accl[JW], accr[JW];
    #pragma unroll
    for (int j = 0; j < JW; ++j) { accl[j] = 0.f; accr[j] = 0.f; }

    #pragma unroll
    for (int c = 0; c < 4; ++c) {       // k-chunks of 16
        float el[16], er[16];
        #pragma unroll
        for (int q = 0; q < 4; ++q) {
            int sl = ((c * 4 + q) ^ (p & 15)) << 2;
            float4 v = *(const float4*)&Ls[(2 * p)     * 64 + sl];
            float4 u = *(const float4*)&Ls[(2 * p + 1) * 64 + sl];
            el[4*q]=v.x; el[4*q+1]=v.y; el[4*q+2]=v.z; el[4*q+3]=v.w;
            er[4*q]=u.x; er[4*q+1]=u.y; er[4*q+2]=u.z; er[4*q+3]=u.w;
        }
        #pragma unroll
        for (int j = 0; j < JW; ++j) {
            const float4* Er = (const float4*)(E + ((j0 + j) << 6) + c * 16);
            #pragma unroll
            for (int q = 0; q < 4; ++q) {
                float4 e = Er[q];
                accl[j] = fmaf(el[4*q+0], e.x, accl[j]);
                accl[j] = fmaf(el[4*q+1], e.y, accl[j]);
                accl[j] = fmaf(el[4*q+2], e.z, accl[j]);
                accl[j] = fmaf(el[4*q+3], e.w, accl[j]);
                accr[j] = fmaf(er[4*q+0], e.x, accr[j]);
                accr[j] = fmaf(er[4*q+1], e.y, accr[j]);
                accr[j] = fmaf(er[4*q+2], e.z, accr[j]);
                accr[j] = fmaf(er[4*q+3], e.w, accr[j]);
            }
        }
    }

    float mbase = ms[2 * p] + ms[2 * p + 1];
    #pragma unroll
    for (int j = 0; j < JW; ++j)
        accl[j] = mbase + __logf(accl[j]) + __logf(accr[j]);

    long prow = ((long)(b * NNODES + g0 + p)) << 6;
    if constexpr (JW >= 4) {
        #pragma unroll
        for (int j4 = 0; j4 < JW; j4 += 4) {
            float4* pg = (float4*)(inside + prow + j0 + j4);
            float4 ev = *pg;
            ev.x += accl[j4]; ev.y += accl[j4+1];
            ev.z += accl[j4+2]; ev.w += accl[j4+3];
            *pg = ev;
        }
    } else {
        float2* pg = (float2*)(inside + prow + j0);
        float2 ev = *pg;
        ev.x += accl[0]; ev.y += accl[1];
        *pg = ev;
    }
}

// ---------------------------------------------------------------------------
// Kernel 4: fused tail, levels d=5..0. One block per batch, wave-per-task,
// E row j in lane j's registers, readlane broadcast. Level 0 -> d_out.
// ---------------------------------------------------------------------------
__global__ __launch_bounds__(256) void ktail(float* __restrict__ inside,
                                             const float* __restrict__ E,
                                             float* __restrict__ out) {
    int b    = blockIdx.x;
    int lane = threadIdx.x & 63;
    int wid  = threadIdx.x >> 6;

    float Ereg[64];
    const float4* E4 = (const float4*)(E + lane * NL_);
    #pragma unroll
    for (int q = 0; q < 16; ++q) {
        float4 v = E4[q];
        Ereg[4*q] = v.x; Ereg[4*q+1] = v.y; Ereg[4*q+2] = v.z; Ereg[4*q+3] = v.w;
    }
    int base = b * NNODES;

    for (int d = 5; d >= 0; --d) {
        int n = 1 << d;
        for (int i = wid; i < n; i += 4) {
            int g    = n - 1 + i;
            int rowC = (base + 2 * g + 1) << 6;
            float lf = inside[rowC + lane];
            float rf = inside[rowC + 64 + lane];
            float ml = lf, mr = rf;
            #pragma unroll
            for (int s = 32; s >= 1; s >>= 1) {
                ml = fmaxf(ml, __shfl_xor(ml, s));
                mr = fmaxf(mr, __shfl_xor(mr, s));
            }
            float el = __expf(lf - ml);
            float er = __expf(rf - mr);
            float accl = 0.f, accr = 0.f;
            #pragma unroll
            for (int k = 0; k < 64; ++k) {
                float ek = __int_as_float(__builtin_amdgcn_readlane(__float_as_int(el), k));
                float rk = __int_as_float(__builtin_amdgcn_readlane(__float_as_int(er), k));
                accl = fmaf(ek, Ereg[k], accl);
                accr = fmaf(rk, Ereg[k], accr);
            }
            int rowG  = (base + g) << 6;
            float res = inside[rowG + lane] + ml + mr + __logf(accl) + __logf(accr);
            if (d == 0) out[b * NL_ + lane] = res;
            else        inside[rowG + lane] = res;
        }
        __syncthreads();
    }
}

// ---------------------------------------------------------------------------
// Launch. ws layout: [E: 4096 f][Wt bf16: 32768 us = 16384 f][inside: 16.7M f]
// ---------------------------------------------------------------------------
extern "C" void kernel_launch(void* const* d_in, const int* in_sizes, int n_in,
                              void* d_out, int out_size, void* d_ws, size_t ws_size,
                              hipStream_t stream) {
    const float* hidden = (const float*)d_in[0];
    const float* W      = (const float*)d_in[1];
    const float* bias   = (const float*)d_in[2];
    const float* trans  = (const float*)d_in[3];
    float* out = (float*)d_out;
    float* E   = (float*)d_ws;
    unsigned short* Wt = (unsigned short*)(E + NL_ * NL_);
    float* inside = E + NL_ * NL_ + (DIN * NL_ / 2);

    kprep<<<(DIN * NL_) / 256, 256, 0, stream>>>(W, trans, Wt, E);
    kgemm<<<(B_ * NNODES) / 64, 256, 0, stream>>>(hidden, Wt, bias, inside);
    // tree levels d=9..6: groups = B*n/64, JS = 16/JW, grid always 1024
    klevel2<16><<<((B_ << 9) >> 6) * 1, 256, 0, stream>>>(inside, E, 9);
    klevel2< 8><<<((B_ << 8) >> 6) * 2, 256, 0, stream>>>(inside, E, 8);
    klevel2< 4><<<((B_ << 7) >> 6) * 4, 256, 0, stream>>>(inside, E, 7);
    klevel2< 2><<<((B_ << 6) >> 6) * 8, 256, 0, stream>>>(inside, E, 6);
    ktail<<<B_, 256, 0, stream>>>(inside, E, out);
}